// Round 2
// baseline (357.894 us; speedup 1.0000x reference)
//
#include <hip/hip_runtime.h>

// Haar 3D LL band: out[b,c,d,h,w] = 2^-1.5 * sum of the 2x2x2 block of x.
// x: (2,16,128,128,128) f32 -> out: (2,16,64,64,64) f32.
// Streaming, memory-bound: 256 MiB read + 32 MiB write (~48 us floor @6.3 TB/s).
//
// Layout: thread -> (bc, dout, hout, w8), w8 in [0,16).
//   loadA = float4 #w8     of each input row (covers input w [4*w8, 4*w8+4))
//   loadB = float4 #(16+w8)                 (covers input w [64+4*w8, ...))
// Each load instruction is a dense 256 B segment across its 16-lane group ->
// fully coalesced. 8 float4 loads (2d x 2h x {A,B}) = 128 B/thread read,
// two float2 stores = 16 B/thread write. 8 independent loads/thread for ILP.

#define BC    32
#define DIN   128
#define HIN   128
#define WIN   128
#define DOUT  64
#define HOUT  64
#define WOUT  64

__global__ __launch_bounds__(256) void WaveletTransform3D_kernel(
    const float* __restrict__ x, float* __restrict__ out) {
    const float SCALE = 0.35355339059327373f; // 2^-1.5

    int tid = blockIdx.x * blockDim.x + threadIdx.x;
    int w8   = tid & 15;
    int t    = tid >> 4;
    int hout = t & 63;
    t >>= 6;
    int dout = t & 63;
    int bc   = t >> 6;

    const int d0 = dout << 1;
    const int h0 = hout << 1;

    const float4* __restrict__ p = reinterpret_cast<const float4*>(x);
    // row base in float4 units (row = 128 floats = 32 float4)
    size_t r00 = (((size_t)(bc * DIN + d0) * HIN + h0) * WIN) >> 2;
    const size_t hs = WIN / 4;             // 32 float4 per h step
    const size_t ds = (size_t)HIN * WIN / 4; // per d step

    const size_t a = r00 + w8;        // first half-row
    const size_t b = r00 + 16 + w8;   // second half-row

    float4 a00 = p[a];
    float4 a01 = p[a + hs];
    float4 a10 = p[a + ds];
    float4 a11 = p[a + ds + hs];
    float4 b00 = p[b];
    float4 b01 = p[b + hs];
    float4 b10 = p[b + ds];
    float4 b11 = p[b + ds + hs];

    float2 oA, oB;
    oA.x = ((a00.x + a00.y) + (a01.x + a01.y) + (a10.x + a10.y) + (a11.x + a11.y)) * SCALE;
    oA.y = ((a00.z + a00.w) + (a01.z + a01.w) + (a10.z + a10.w) + (a11.z + a11.w)) * SCALE;
    oB.x = ((b00.x + b00.y) + (b01.x + b01.y) + (b10.x + b10.y) + (b11.x + b11.y)) * SCALE;
    oB.y = ((b00.z + b00.w) + (b01.z + b01.w) + (b10.z + b10.w) + (b11.z + b11.w)) * SCALE;

    size_t orow = ((size_t)(bc * DOUT + dout) * HOUT + hout) * WOUT;
    *reinterpret_cast<float2*>(out + orow + (w8 << 1))      = oA; // out w = 2*w8, 2*w8+1
    *reinterpret_cast<float2*>(out + orow + 32 + (w8 << 1)) = oB; // out w = 32+2*w8, ...
}

extern "C" void kernel_launch(void* const* d_in, const int* in_sizes, int n_in,
                              void* d_out, int out_size, void* d_ws, size_t ws_size,
                              hipStream_t stream) {
    const float* x = (const float*)d_in[0];
    float* out = (float*)d_out;
    // threads: BC * DOUT * HOUT * 16 = 32*64*64*16 = 2,097,152
    const int total = BC * DOUT * HOUT * 16;
    const int block = 256;
    const int grid = total / block; // 8192
    WaveletTransform3D_kernel<<<grid, block, 0, stream>>>(x, out);
}

// Round 4
// 340.060 us; speedup vs baseline: 1.0524x; 1.0524x over previous
//
#include <hip/hip_runtime.h>

// Haar 3D LL band: out[b,c,d,h,w] = 2^-1.5 * sum of the 2x2x2 block of x.
// x: (2,16,128,128,128) f32 -> out: (2,16,64,64,64) f32.
// Streaming, memory-bound: 256 MiB read + 32 MiB write (~48 us floor @6.3 TB/s).
//
// Thread -> (bc, dout, hout, w8), w8 in [0,16).
//   loadA = float4 #w8      (input w [4*w8, 4*w8+4))   -- first half-row
//   loadB = float4 #(16+w8) (input w [64+4*w8, ...))   -- second half-row
// Every load instruction covers a dense 256 B segment per 16-lane group.
// 8 vec4 loads = 128 B/thread read; 2 vec2 stores = 16 B/thread write.
// Nontemporal loads/stores: pure streams, zero reuse, input exactly L3-sized.
// Note: __builtin_nontemporal_* requires clang ext_vector_type, not HIP float4.

typedef float v4f __attribute__((ext_vector_type(4)));
typedef float v2f __attribute__((ext_vector_type(2)));

#define BC    32
#define DIN   128
#define HIN   128
#define WIN   128
#define DOUT  64
#define HOUT  64
#define WOUT  64

__global__ __launch_bounds__(256) void WaveletTransform3D_kernel(
    const float* __restrict__ x, float* __restrict__ out) {
    const float SCALE = 0.35355339059327373f; // 2^-1.5

    int tid = blockIdx.x * blockDim.x + threadIdx.x;
    int w8   = tid & 15;
    int t    = tid >> 4;
    int hout = t & 63;
    t >>= 6;
    int dout = t & 63;
    int bc   = t >> 6;

    const int d0 = dout << 1;
    const int h0 = hout << 1;

    const v4f* __restrict__ p = reinterpret_cast<const v4f*>(x);
    size_t r00 = (((size_t)(bc * DIN + d0) * HIN + h0) * WIN) >> 2;
    const size_t hs = WIN / 4;               // 32 vec4 per h step
    const size_t ds = (size_t)HIN * WIN / 4; // 4096 vec4 per d step

    const size_t a = r00 + w8;
    const size_t b = r00 + 16 + w8;

    v4f a00 = __builtin_nontemporal_load(p + a);
    v4f a01 = __builtin_nontemporal_load(p + a + hs);
    v4f a10 = __builtin_nontemporal_load(p + a + ds);
    v4f a11 = __builtin_nontemporal_load(p + a + ds + hs);
    v4f b00 = __builtin_nontemporal_load(p + b);
    v4f b01 = __builtin_nontemporal_load(p + b + hs);
    v4f b10 = __builtin_nontemporal_load(p + b + ds);
    v4f b11 = __builtin_nontemporal_load(p + b + ds + hs);

    v2f oA, oB;
    oA.x = ((a00.x + a00.y) + (a01.x + a01.y) + (a10.x + a10.y) + (a11.x + a11.y)) * SCALE;
    oA.y = ((a00.z + a00.w) + (a01.z + a01.w) + (a10.z + a10.w) + (a11.z + a11.w)) * SCALE;
    oB.x = ((b00.x + b00.y) + (b01.x + b01.y) + (b10.x + b10.y) + (b11.x + b11.y)) * SCALE;
    oB.y = ((b00.z + b00.w) + (b01.z + b01.w) + (b10.z + b10.w) + (b11.z + b11.w)) * SCALE;

    size_t orow = ((size_t)(bc * DOUT + dout) * HOUT + hout) * WOUT;
    __builtin_nontemporal_store(oA, reinterpret_cast<v2f*>(out + orow + (w8 << 1)));
    __builtin_nontemporal_store(oB, reinterpret_cast<v2f*>(out + orow + 32 + (w8 << 1)));
}

extern "C" void kernel_launch(void* const* d_in, const int* in_sizes, int n_in,
                              void* d_out, int out_size, void* d_ws, size_t ws_size,
                              hipStream_t stream) {
    const float* x = (const float*)d_in[0];
    float* out = (float*)d_out;
    const int total = BC * DOUT * HOUT * 16; // 2,097,152 threads
    const int block = 256;
    const int grid = total / block;          // 8192 blocks
    WaveletTransform3D_kernel<<<grid, block, 0, stream>>>(x, out);
}